// Round 1
// baseline (710.517 us; speedup 1.0000x reference)
//
#include <hip/hip_runtime.h>
#include <hip/hip_bf16.h>

#define NN 100000
#define EE 500000
#define DD 128
#define NDEPTH 2
#define EPSV 1e-5f

typedef __attribute__((ext_vector_type(4))) float f32x4;
typedef __attribute__((ext_vector_type(8))) short bf16x8;

static __device__ __forceinline__ short f2bf(float x) {
  union { float f; unsigned u; } v; v.f = x;
  unsigned r = v.u + 0x7fffu + ((v.u >> 16) & 1u);  // round-to-nearest-even
  return (short)(r >> 16);
}

// ---- convert both weight tensors to bf16 once ----
__global__ void k_convert_w(const float* __restrict__ lw, const float* __restrict__ gw,
                            short* __restrict__ wbf) {
  int i = blockIdx.x * 256 + threadIdx.x;
  if (i < NDEPTH * DD * DD) {
    wbf[i] = f2bf(lw[i]);
    wbf[NDEPTH * DD * DD + i] = f2bf(gw[i]);
  }
}

// ---- edge pass 1: degree (weighted) + count histogram by col ----
__global__ void k_edge1(const int* __restrict__ ei, const float* __restrict__ ew,
                        float* __restrict__ deg, int* __restrict__ cnt) {
  int e = blockIdx.x * 256 + threadIdx.x;
  if (e < EE) {
    int c = ei[EE + e];
    atomicAdd(deg + c, ew[e]);
    atomicAdd(cnt + c, 1);
  }
}

__global__ void k_dinv(const float* __restrict__ deg, float* __restrict__ dinv) {
  int i = blockIdx.x * 256 + threadIdx.x;
  if (i < NN) {
    float d = deg[i];
    dinv[i] = d > 0.f ? rsqrtf(d) : 0.f;
  }
}

// ---- exclusive scan of cnt -> rowptr, cursor (single block, 1024 threads) ----
__global__ void k_scan(const int* __restrict__ cnt, int* __restrict__ rowptr,
                       int* __restrict__ cursor) {
  __shared__ int part[1024];
  int t = threadIdx.x;
  const int CH = (NN + 1023) / 1024;  // 98
  int lo = t * CH, hi = lo + CH; if (hi > NN) hi = NN;
  int s = 0;
  for (int i = lo; i < hi; ++i) s += cnt[i];
  part[t] = s;
  __syncthreads();
  for (int off = 1; off < 1024; off <<= 1) {
    int v = part[t];
    int u = (t >= off) ? part[t - off] : 0;
    __syncthreads();
    part[t] = v + u;
    __syncthreads();
  }
  int base = (t == 0) ? 0 : part[t - 1];
  for (int i = lo; i < hi; ++i) {
    rowptr[i] = base; cursor[i] = base; base += cnt[i];
  }
  if (t == 1023) rowptr[NN] = part[1023];
}

// ---- edge pass 2: bucket (row, norm) by col ----
__global__ void k_edge2(const int* __restrict__ ei, const float* __restrict__ ew,
                        const float* __restrict__ dinv, int* __restrict__ cursor,
                        int* __restrict__ srow, float* __restrict__ snorm) {
  int e = blockIdx.x * 256 + threadIdx.x;
  if (e < EE) {
    int r = ei[e], c = ei[EE + e];
    float nrm = dinv[r] * ew[e] * dinv[c];
    int pos = atomicAdd(cursor + c, 1);
    srow[pos] = r;
    snorm[pos] = nrm;
  }
}

// ---- dual GEMM: Ol = H @ Wl^T, Og = H @ Wg^T  (one wave = 16 rows x 128 cols, both outputs)
__global__ __launch_bounds__(256) void k_dualgemm(const float* __restrict__ H,
    const short* __restrict__ Wl, const short* __restrict__ Wg,
    float* __restrict__ Ol, float* __restrict__ Og) {
  int wid = (blockIdx.x * 256 + (int)threadIdx.x) >> 6;
  int lane = threadIdx.x & 63;
  if (wid >= NN / 16) return;
  int row0 = wid << 4;
  int m = lane & 15, g = lane >> 4;

  // A fragments: H[row0+m][s*32 + g*8 + j], j=0..7 (contiguous 32B per lane)
  const float* hrow = H + (size_t)(row0 + m) * DD + g * 8;
  bf16x8 a[4];
#pragma unroll
  for (int s = 0; s < 4; ++s) {
    f32x4 v0 = *(const f32x4*)(hrow + s * 32);
    f32x4 v1 = *(const f32x4*)(hrow + s * 32 + 4);
    bf16x8 t;
    t[0] = f2bf(v0[0]); t[1] = f2bf(v0[1]); t[2] = f2bf(v0[2]); t[3] = f2bf(v0[3]);
    t[4] = f2bf(v1[0]); t[5] = f2bf(v1[1]); t[6] = f2bf(v1[2]); t[7] = f2bf(v1[3]);
    a[s] = t;
  }

  f32x4 accl[8], accg[8];
#pragma unroll
  for (int t = 0; t < 8; ++t) {
    f32x4 z; z[0] = 0.f; z[1] = 0.f; z[2] = 0.f; z[3] = 0.f;
    accl[t] = z; accg[t] = z;
  }

#pragma unroll
  for (int s = 0; s < 4; ++s) {
#pragma unroll
    for (int t = 0; t < 8; ++t) {
      int off = (t * 16 + m) * DD + s * 32 + g * 8;  // W[d][k], k contiguous
      bf16x8 bl = *(const bf16x8*)(Wl + off);
      bf16x8 bg = *(const bf16x8*)(Wg + off);
      accl[t] = __builtin_amdgcn_mfma_f32_16x16x32_bf16(a[s], bl, accl[t], 0, 0, 0);
      accg[t] = __builtin_amdgcn_mfma_f32_16x16x32_bf16(a[s], bg, accg[t], 0, 0, 0);
    }
  }

  // C/D layout (verified m89): col = lane&15, row = (lane>>4)*4 + i
#pragma unroll
  for (int t = 0; t < 8; ++t) {
#pragma unroll
    for (int i = 0; i < 4; ++i) {
      int idx = (row0 + g * 4 + i) * DD + t * 16 + m;
      Ol[idx] = accl[t][i];
      Og[idx] = accg[t][i];
    }
  }
}

// ---- aggregation: one wave per node, tmp[node] += sum norm * hg[srcrow] ----
__global__ __launch_bounds__(256) void k_agg(const int* __restrict__ rowptr,
    const int* __restrict__ srow, const float* __restrict__ snorm,
    const float* __restrict__ hg, float* __restrict__ tmp) {
  int node = (blockIdx.x * 256 + (int)threadIdx.x) >> 6;
  int lane = threadIdx.x & 63;
  if (node >= NN) return;
  node = __builtin_amdgcn_readfirstlane(node);
  int beg = rowptr[node], end = rowptr[node + 1];
  float ax = 0.f, ay = 0.f;
  for (int j = beg; j < end; ++j) {
    int r = srow[j];
    float w = snorm[j];
    const float* p = hg + (size_t)r * DD + lane * 2;
    ax += w * p[0];
    ay += w * p[1];
  }
  float* t = tmp + (size_t)node * DD + lane * 2;
  t[0] += ax;
  t[1] += ay;
}

// ---- BN stats: column sums + sumsq (per-block partial, then atomics) ----
__global__ void k_bnstats(const float* __restrict__ h, float* __restrict__ sums) {
  int d = threadIdx.x & (DD - 1);
  int half = threadIdx.x >> 7;
  int row0 = blockIdx.x * 512;
  int rend = row0 + 512; if (rend > NN) rend = NN;
  float s = 0.f, ss = 0.f;
  for (int r = row0 + half; r < rend; r += 2) {
    float v = h[(size_t)r * DD + d];
    s += v; ss += v * v;
  }
  atomicAdd(sums + d, s);
  atomicAdd(sums + DD + d, ss);
}

// ---- BN apply (+ optional ReLU) ----
__global__ void k_bnapply(const float* __restrict__ h, const float* __restrict__ sums,
                          const float* __restrict__ gamma, const float* __restrict__ beta,
                          float* __restrict__ out, int relu) {
  int i = blockIdx.x * 256 + threadIdx.x;  // over N*D/4
  if (i >= NN * DD / 4) return;
  int d0 = (i * 4) & (DD - 1);
  f32x4 v = ((const f32x4*)h)[i];
  f32x4 o;
#pragma unroll
  for (int c = 0; c < 4; ++c) {
    float mean = sums[d0 + c] * (1.f / NN);
    float var = sums[DD + d0 + c] * (1.f / NN) - mean * mean;
    float inv = rsqrtf(var + EPSV);
    float x = (v[c] - mean) * inv * gamma[d0 + c] + beta[d0 + c];
    o[c] = relu ? fmaxf(x, 0.f) : x;
  }
  ((f32x4*)out)[i] = o;
}

extern "C" void kernel_launch(void* const* d_in, const int* in_sizes, int n_in,
                              void* d_out, int out_size, void* d_ws, size_t ws_size,
                              hipStream_t stream) {
  const float* x     = (const float*)d_in[0];
  const int*   ei    = (const int*)d_in[1];
  const float* ew    = (const float*)d_in[2];
  const float* lin_w = (const float*)d_in[3];
  const float* gcn_w = (const float*)d_in[4];
  const float* gamma = (const float*)d_in[5];
  const float* beta  = (const float*)d_in[6];
  float* out = (float*)d_out;

  char* ws = (char*)d_ws;
  size_t off = 0;
  auto alloc = [&](size_t bytes) -> void* {
    void* p = ws + off;
    off += (bytes + 255) & ~(size_t)255;
    return p;
  };
  float* hg     = (float*)alloc((size_t)NN * DD * 4);
  float* tmp    = (float*)alloc((size_t)NN * DD * 4);
  float* snorm  = (float*)alloc((size_t)EE * 4);
  int*   srow   = (int*)alloc((size_t)EE * 4);
  float* deg    = (float*)alloc((size_t)NN * 4);
  float* dinv   = (float*)alloc((size_t)NN * 4);
  int*   rowptr = (int*)alloc((size_t)(NN + 1) * 4);
  int*   cursor = (int*)alloc((size_t)NN * 4);
  int*   cnt    = (int*)alloc((size_t)NN * 4);
  short* wbf    = (short*)alloc((size_t)2 * NDEPTH * DD * DD * 2);
  float* sums   = (float*)alloc((size_t)2 * DD * 4);

  hipMemsetAsync(deg, 0, (size_t)NN * 4, stream);
  hipMemsetAsync(cnt, 0, (size_t)NN * 4, stream);

  k_convert_w<<<(NDEPTH * DD * DD + 255) / 256, 256, 0, stream>>>(lin_w, gcn_w, wbf);
  k_edge1<<<(EE + 255) / 256, 256, 0, stream>>>(ei, ew, deg, cnt);
  k_dinv<<<(NN + 255) / 256, 256, 0, stream>>>(deg, dinv);
  k_scan<<<1, 1024, 0, stream>>>(cnt, rowptr, cursor);
  k_edge2<<<(EE + 255) / 256, 256, 0, stream>>>(ei, ew, dinv, cursor, srow, snorm);

  const float* hin = x;
  for (int L = 0; L < NDEPTH; ++L) {
    const short* Wl = wbf + (size_t)L * DD * DD;
    const short* Wg = wbf + (size_t)NDEPTH * DD * DD + (size_t)L * DD * DD;
    // tmp = hin @ lin_w^T ; hg = hin @ gcn_w^T
    k_dualgemm<<<(NN / 16 + 3) / 4, 256, 0, stream>>>(hin, Wl, Wg, tmp, hg);
    // tmp += scatter-aggregate(norm * hg[row] -> col)
    k_agg<<<(NN + 3) / 4, 256, 0, stream>>>(rowptr, srow, snorm, hg, tmp);
    // BatchNorm (+ ReLU except last layer)
    hipMemsetAsync(sums, 0, (size_t)2 * DD * 4, stream);
    k_bnstats<<<(NN + 511) / 512, 256, 0, stream>>>(tmp, sums);
    k_bnapply<<<(NN * DD / 4 + 255) / 256, 256, 0, stream>>>(
        tmp, sums, gamma + (size_t)L * DD, beta + (size_t)L * DD, out, (L < NDEPTH - 1) ? 1 : 0);
    hin = out;
  }
}

// Round 5
// 493.612 us; speedup vs baseline: 1.4394x; 1.4394x over previous
//
#include <hip/hip_runtime.h>
#include <hip/hip_bf16.h>

#define NN 100000
#define EE 500000
#define DD 128
#define NDEPTH 2
#define EPSV 1e-5f
#define NCHUNK 1024
#define NBLK ((NN + NCHUNK - 1) / NCHUNK)   // 98

typedef __attribute__((ext_vector_type(4))) float f32x4;
typedef __attribute__((ext_vector_type(4))) int i32x4;
typedef __attribute__((ext_vector_type(8))) short bf16x8;

static __device__ __forceinline__ short f2bf(float x) {
  union { float f; unsigned u; } v; v.f = x;
  unsigned r = v.u + 0x7fffu + ((v.u >> 16) & 1u);  // round-to-nearest-even
  return (short)(r >> 16);
}

// ---- convert both weight tensors to bf16 once ----
__global__ void k_convert_w(const float* __restrict__ lw, const float* __restrict__ gw,
                            short* __restrict__ wbf) {
  int i = blockIdx.x * 256 + threadIdx.x;
  if (i < NDEPTH * DD * DD) {
    wbf[i] = f2bf(lw[i]);
    wbf[NDEPTH * DD * DD + i] = f2bf(gw[i]);
  }
}

// ---- edge pass 1: degree (weighted) + count histogram by col ----
__global__ void k_edge1(const int* __restrict__ ei, const float* __restrict__ ew,
                        float* __restrict__ deg, int* __restrict__ cnt) {
  int e = blockIdx.x * 256 + threadIdx.x;
  if (e < EE) {
    int c = ei[EE + e];
    atomicAdd(deg + c, ew[e]);
    atomicAdd(cnt + c, 1);
  }
}

__global__ void k_dinv(const float* __restrict__ deg, float* __restrict__ dinv) {
  int i = blockIdx.x * 256 + threadIdx.x;
  if (i < NN) {
    float d = deg[i];
    dinv[i] = d > 0.f ? rsqrtf(d) : 0.f;
  }
}

// ---- scan stage 1: per-chunk (1024 elems) sums ----
__global__ __launch_bounds__(256) void k_scan_part(const int* __restrict__ cnt,
                                                   int* __restrict__ part) {
  int b = blockIdx.x, t = threadIdx.x, lane = t & 63, wid = t >> 6;
  int base = b * NCHUNK + t * 4;
  int s = 0;
  if (base + 3 < NN) {
    i32x4 v = *(const i32x4*)(cnt + base);
    s = v[0] + v[1] + v[2] + v[3];
  } else {
    for (int j = 0; j < 4; ++j) if (base + j < NN) s += cnt[base + j];
  }
  // wave reduce
  for (int d = 32; d > 0; d >>= 1) s += __shfl_down(s, d);
  __shared__ int wsum[4];
  if (lane == 0) wsum[wid] = s;
  __syncthreads();
  if (t == 0) part[b] = wsum[0] + wsum[1] + wsum[2] + wsum[3];
}

// ---- scan stage 2: exclusive scan of the 98 partials (1 small block) ----
__global__ void k_scan_mid(int* __restrict__ part, int* __restrict__ rowptr) {
  __shared__ int sm[128];
  int t = threadIdx.x;
  int v = (t < NBLK) ? part[t] : 0;
  sm[t] = v;
  __syncthreads();
  for (int off = 1; off < 128; off <<= 1) {
    int a = sm[t];
    int b = (t >= off) ? sm[t - off] : 0;
    __syncthreads();
    sm[t] = a + b;
    __syncthreads();
  }
  if (t < NBLK) part[t] = (t == 0) ? 0 : sm[t - 1];  // exclusive chunk offset
  if (t == 127) rowptr[NN] = sm[127];                // total = E
}

// ---- scan stage 3: per-chunk exclusive scan + chunk offset -> rowptr, cursor ----
__global__ __launch_bounds__(256) void k_scan_final(const int* __restrict__ cnt,
    const int* __restrict__ part, int* __restrict__ rowptr, int* __restrict__ cursor) {
  int b = blockIdx.x, t = threadIdx.x, lane = t & 63, wid = t >> 6;
  int base = b * NCHUNK + t * 4;
  int c0 = 0, c1 = 0, c2 = 0, c3 = 0;
  if (base + 3 < NN) {
    i32x4 v = *(const i32x4*)(cnt + base);
    c0 = v[0]; c1 = v[1]; c2 = v[2]; c3 = v[3];
  } else {
    if (base < NN) c0 = cnt[base];
    if (base + 1 < NN) c1 = cnt[base + 1];
    if (base + 2 < NN) c2 = cnt[base + 2];
    if (base + 3 < NN) c3 = cnt[base + 3];
  }
  int s = c0 + c1 + c2 + c3;
  int v = s;
  for (int d = 1; d < 64; d <<= 1) {
    int u = __shfl_up(v, d);
    if (lane >= d) v += u;
  }
  __shared__ int wsum[4];
  if (lane == 63) wsum[wid] = v;
  __syncthreads();
  int woff = 0;
  for (int w = 0; w < wid; ++w) woff += wsum[w];
  int excl = part[b] + woff + (v - s);
  if (base < NN)     { rowptr[base]     = excl; cursor[base]     = excl; excl += c0; }
  if (base + 1 < NN) { rowptr[base + 1] = excl; cursor[base + 1] = excl; excl += c1; }
  if (base + 2 < NN) { rowptr[base + 2] = excl; cursor[base + 2] = excl; excl += c2; }
  if (base + 3 < NN) { rowptr[base + 3] = excl; cursor[base + 3] = excl; }
}

// ---- edge pass 2: bucket (row, norm) by col ----
__global__ void k_edge2(const int* __restrict__ ei, const float* __restrict__ ew,
                        const float* __restrict__ dinv, int* __restrict__ cursor,
                        int* __restrict__ srow, float* __restrict__ snorm) {
  int e = blockIdx.x * 256 + threadIdx.x;
  if (e < EE) {
    int r = ei[e], c = ei[EE + e];
    float nrm = dinv[r] * ew[e] * dinv[c];
    int pos = atomicAdd(cursor + c, 1);
    srow[pos] = r;
    snorm[pos] = nrm;
  }
}

// ---- dual GEMM: Ol = H @ Wl^T, Og = H @ Wg^T  (one wave = 16 rows x 128 cols, both outputs)
__global__ __launch_bounds__(256) void k_dualgemm(const float* __restrict__ H,
    const short* __restrict__ Wl, const short* __restrict__ Wg,
    float* __restrict__ Ol, float* __restrict__ Og) {
  int wid = (blockIdx.x * 256 + (int)threadIdx.x) >> 6;
  int lane = threadIdx.x & 63;
  if (wid >= NN / 16) return;
  int row0 = wid << 4;
  int m = lane & 15, g = lane >> 4;

  const float* hrow = H + (size_t)(row0 + m) * DD + g * 8;
  bf16x8 a[4];
#pragma unroll
  for (int s = 0; s < 4; ++s) {
    f32x4 v0 = *(const f32x4*)(hrow + s * 32);
    f32x4 v1 = *(const f32x4*)(hrow + s * 32 + 4);
    bf16x8 t;
    t[0] = f2bf(v0[0]); t[1] = f2bf(v0[1]); t[2] = f2bf(v0[2]); t[3] = f2bf(v0[3]);
    t[4] = f2bf(v1[0]); t[5] = f2bf(v1[1]); t[6] = f2bf(v1[2]); t[7] = f2bf(v1[3]);
    a[s] = t;
  }

  f32x4 accl[8], accg[8];
#pragma unroll
  for (int t = 0; t < 8; ++t) {
    f32x4 z; z[0] = 0.f; z[1] = 0.f; z[2] = 0.f; z[3] = 0.f;
    accl[t] = z; accg[t] = z;
  }

#pragma unroll
  for (int s = 0; s < 4; ++s) {
#pragma unroll
    for (int t = 0; t < 8; ++t) {
      int off = (t * 16 + m) * DD + s * 32 + g * 8;
      bf16x8 bl = *(const bf16x8*)(Wl + off);
      bf16x8 bg = *(const bf16x8*)(Wg + off);
      accl[t] = __builtin_amdgcn_mfma_f32_16x16x32_bf16(a[s], bl, accl[t], 0, 0, 0);
      accg[t] = __builtin_amdgcn_mfma_f32_16x16x32_bf16(a[s], bg, accg[t], 0, 0, 0);
    }
  }

#pragma unroll
  for (int t = 0; t < 8; ++t) {
#pragma unroll
    for (int i = 0; i < 4; ++i) {
      int idx = (row0 + g * 4 + i) * DD + t * 16 + m;
      Ol[idx] = accl[t][i];
      Og[idx] = accg[t][i];
    }
  }
}

// ---- aggregation: one wave per node, tmp[node] += sum norm * hg[srcrow] ----
__global__ __launch_bounds__(256) void k_agg(const int* __restrict__ rowptr,
    const int* __restrict__ srow, const float* __restrict__ snorm,
    const float* __restrict__ hg, float* __restrict__ tmp) {
  int node = (blockIdx.x * 256 + (int)threadIdx.x) >> 6;
  int lane = threadIdx.x & 63;
  if (node >= NN) return;
  node = __builtin_amdgcn_readfirstlane(node);
  int beg = rowptr[node], end = rowptr[node + 1];
  float ax = 0.f, ay = 0.f;
  for (int j = beg; j < end; ++j) {
    int r = srow[j];
    float w = snorm[j];
    const float* p = hg + (size_t)r * DD + lane * 2;
    ax += w * p[0];
    ay += w * p[1];
  }
  float* t = tmp + (size_t)node * DD + lane * 2;
  t[0] += ax;
  t[1] += ay;
}

// ---- BN stats: column sums + sumsq (per-block partial, then atomics) ----
__global__ void k_bnstats(const float* __restrict__ h, float* __restrict__ sums) {
  int d = threadIdx.x & (DD - 1);
  int half = threadIdx.x >> 7;
  int row0 = blockIdx.x * 512;
  int rend = row0 + 512; if (rend > NN) rend = NN;
  float s = 0.f, ss = 0.f;
  for (int r = row0 + half; r < rend; r += 2) {
    float v = h[(size_t)r * DD + d];
    s += v; ss += v * v;
  }
  atomicAdd(sums + d, s);
  atomicAdd(sums + DD + d, ss);
}

// ---- BN apply (+ optional ReLU) ----
__global__ void k_bnapply(const float* __restrict__ h, const float* __restrict__ sums,
                          const float* __restrict__ gamma, const float* __restrict__ beta,
                          float* __restrict__ out, int relu) {
  int i = blockIdx.x * 256 + threadIdx.x;
  if (i >= NN * DD / 4) return;
  int d0 = (i * 4) & (DD - 1);
  f32x4 v = ((const f32x4*)h)[i];
  f32x4 o;
#pragma unroll
  for (int c = 0; c < 4; ++c) {
    float mean = sums[d0 + c] * (1.f / NN);
    float var = sums[DD + d0 + c] * (1.f / NN) - mean * mean;
    float inv = rsqrtf(var + EPSV);
    float x = (v[c] - mean) * inv * gamma[d0 + c] + beta[d0 + c];
    o[c] = relu ? fmaxf(x, 0.f) : x;
  }
  ((f32x4*)out)[i] = o;
}

extern "C" void kernel_launch(void* const* d_in, const int* in_sizes, int n_in,
                              void* d_out, int out_size, void* d_ws, size_t ws_size,
                              hipStream_t stream) {
  const float* x     = (const float*)d_in[0];
  const int*   ei    = (const int*)d_in[1];
  const float* ew    = (const float*)d_in[2];
  const float* lin_w = (const float*)d_in[3];
  const float* gcn_w = (const float*)d_in[4];
  const float* gamma = (const float*)d_in[5];
  const float* beta  = (const float*)d_in[6];
  float* out = (float*)d_out;

  char* ws = (char*)d_ws;
  size_t off = 0;
  auto alloc = [&](size_t bytes) -> void* {
    void* p = ws + off;
    off += (bytes + 255) & ~(size_t)255;
    return p;
  };
  float* hg     = (float*)alloc((size_t)NN * DD * 4);
  float* tmp    = (float*)alloc((size_t)NN * DD * 4);
  float* snorm  = (float*)alloc((size_t)EE * 4);
  int*   srow   = (int*)alloc((size_t)EE * 4);
  float* deg    = (float*)alloc((size_t)NN * 4);
  float* dinv   = (float*)alloc((size_t)NN * 4);
  int*   rowptr = (int*)alloc((size_t)(NN + 1) * 4);
  int*   cursor = (int*)alloc((size_t)NN * 4);
  int*   cnt    = (int*)alloc((size_t)NN * 4);
  int*   part   = (int*)alloc((size_t)NBLK * 4);
  short* wbf    = (short*)alloc((size_t)2 * NDEPTH * DD * DD * 2);
  float* sums   = (float*)alloc((size_t)2 * DD * 4);

  hipMemsetAsync(deg, 0, (size_t)NN * 4, stream);
  hipMemsetAsync(cnt, 0, (size_t)NN * 4, stream);

  k_convert_w<<<(NDEPTH * DD * DD + 255) / 256, 256, 0, stream>>>(lin_w, gcn_w, wbf);
  k_edge1<<<(EE + 255) / 256, 256, 0, stream>>>(ei, ew, deg, cnt);
  k_dinv<<<(NN + 255) / 256, 256, 0, stream>>>(deg, dinv);
  k_scan_part<<<NBLK, 256, 0, stream>>>(cnt, part);
  k_scan_mid<<<1, 128, 0, stream>>>(part, rowptr);
  k_scan_final<<<NBLK, 256, 0, stream>>>(cnt, part, rowptr, cursor);
  k_edge2<<<(EE + 255) / 256, 256, 0, stream>>>(ei, ew, dinv, cursor, srow, snorm);

  const float* hin = x;
  for (int L = 0; L < NDEPTH; ++L) {
    const short* Wl = wbf + (size_t)L * DD * DD;
    const short* Wg = wbf + (size_t)NDEPTH * DD * DD + (size_t)L * DD * DD;
    k_dualgemm<<<(NN / 16 + 3) / 4, 256, 0, stream>>>(hin, Wl, Wg, tmp, hg);
    k_agg<<<(NN + 3) / 4, 256, 0, stream>>>(rowptr, srow, snorm, hg, tmp);
    hipMemsetAsync(sums, 0, (size_t)2 * DD * 4, stream);
    k_bnstats<<<(NN + 511) / 512, 256, 0, stream>>>(tmp, sums);
    k_bnapply<<<(NN * DD / 4 + 255) / 256, 256, 0, stream>>>(
        tmp, sums, gamma + (size_t)L * DD, beta + (size_t)L * DD, out, (L < NDEPTH - 1) ? 1 : 0);
    hin = out;
  }
}

// Round 6
// 391.709 us; speedup vs baseline: 1.8139x; 1.2601x over previous
//
#include <hip/hip_runtime.h>
#include <hip/hip_bf16.h>

#define NN 100000
#define EE 500000
#define DD 128
#define NDEPTH 2
#define EPSV 1e-5f
#define NCHUNK 1024
#define NBLK ((NN + NCHUNK - 1) / NCHUNK)   // 98
#define NPB 2000     // bnstats blocks
#define RPB 50       // rows per bnstats block (2000*50 = 100000)

typedef __attribute__((ext_vector_type(4))) float f32x4;
typedef __attribute__((ext_vector_type(4))) int i32x4;
typedef __attribute__((ext_vector_type(8))) short bf16x8;
typedef __attribute__((ext_vector_type(4))) short bf16x4;

static __device__ __forceinline__ short f2bf(float x) {
  union { float f; unsigned u; } v; v.f = x;
  unsigned r = v.u + 0x7fffu + ((v.u >> 16) & 1u);  // round-to-nearest-even
  return (short)(r >> 16);
}
static __device__ __forceinline__ float bfbits2f(unsigned hi16) {
  union { unsigned u; float f; } v; v.u = hi16;
  return v.f;
}

// ---- convert both weight tensors to bf16 once ----
__global__ void k_convert_w(const float* __restrict__ lw, const float* __restrict__ gw,
                            short* __restrict__ wbf) {
  int i = blockIdx.x * 256 + threadIdx.x;
  if (i < NDEPTH * DD * DD) {
    wbf[i] = f2bf(lw[i]);
    wbf[NDEPTH * DD * DD + i] = f2bf(gw[i]);
  }
}

// ---- edge pass 1: degree (weighted) + count histogram by col ----
__global__ void k_edge1(const int* __restrict__ ei, const float* __restrict__ ew,
                        float* __restrict__ deg, int* __restrict__ cnt) {
  int e = blockIdx.x * 256 + threadIdx.x;
  if (e < EE) {
    int c = ei[EE + e];
    atomicAdd(deg + c, ew[e]);
    atomicAdd(cnt + c, 1);
  }
}

__global__ void k_dinv(const float* __restrict__ deg, float* __restrict__ dinv) {
  int i = blockIdx.x * 256 + threadIdx.x;
  if (i < NN) {
    float d = deg[i];
    dinv[i] = d > 0.f ? rsqrtf(d) : 0.f;
  }
}

// ---- scan stage 1: per-chunk (1024 elems) sums ----
__global__ __launch_bounds__(256) void k_scan_part(const int* __restrict__ cnt,
                                                   int* __restrict__ part) {
  int b = blockIdx.x, t = threadIdx.x, lane = t & 63, wid = t >> 6;
  int base = b * NCHUNK + t * 4;
  int s = 0;
  if (base + 3 < NN) {
    i32x4 v = *(const i32x4*)(cnt + base);
    s = v[0] + v[1] + v[2] + v[3];
  } else {
    for (int j = 0; j < 4; ++j) if (base + j < NN) s += cnt[base + j];
  }
  for (int d = 32; d > 0; d >>= 1) s += __shfl_down(s, d);
  __shared__ int wsum[4];
  if (lane == 0) wsum[wid] = s;
  __syncthreads();
  if (t == 0) part[b] = wsum[0] + wsum[1] + wsum[2] + wsum[3];
}

// ---- scan stage 2: exclusive scan of the 98 partials ----
__global__ void k_scan_mid(int* __restrict__ part, int* __restrict__ rowptr) {
  __shared__ int sm[128];
  int t = threadIdx.x;
  int v = (t < NBLK) ? part[t] : 0;
  sm[t] = v;
  __syncthreads();
  for (int off = 1; off < 128; off <<= 1) {
    int a = sm[t];
    int b = (t >= off) ? sm[t - off] : 0;
    __syncthreads();
    sm[t] = a + b;
    __syncthreads();
  }
  if (t < NBLK) part[t] = (t == 0) ? 0 : sm[t - 1];
  if (t == 127) rowptr[NN] = sm[127];
}

// ---- scan stage 3: per-chunk exclusive scan -> rowptr, cursor ----
__global__ __launch_bounds__(256) void k_scan_final(const int* __restrict__ cnt,
    const int* __restrict__ part, int* __restrict__ rowptr, int* __restrict__ cursor) {
  int b = blockIdx.x, t = threadIdx.x, lane = t & 63, wid = t >> 6;
  int base = b * NCHUNK + t * 4;
  int c0 = 0, c1 = 0, c2 = 0, c3 = 0;
  if (base + 3 < NN) {
    i32x4 v = *(const i32x4*)(cnt + base);
    c0 = v[0]; c1 = v[1]; c2 = v[2]; c3 = v[3];
  } else {
    if (base < NN) c0 = cnt[base];
    if (base + 1 < NN) c1 = cnt[base + 1];
    if (base + 2 < NN) c2 = cnt[base + 2];
    if (base + 3 < NN) c3 = cnt[base + 3];
  }
  int s = c0 + c1 + c2 + c3;
  int v = s;
  for (int d = 1; d < 64; d <<= 1) {
    int u = __shfl_up(v, d);
    if (lane >= d) v += u;
  }
  __shared__ int wsum[4];
  if (lane == 63) wsum[wid] = v;
  __syncthreads();
  int woff = 0;
  for (int w = 0; w < wid; ++w) woff += wsum[w];
  int excl = part[b] + woff + (v - s);
  if (base < NN)     { rowptr[base]     = excl; cursor[base]     = excl; excl += c0; }
  if (base + 1 < NN) { rowptr[base + 1] = excl; cursor[base + 1] = excl; excl += c1; }
  if (base + 2 < NN) { rowptr[base + 2] = excl; cursor[base + 2] = excl; excl += c2; }
  if (base + 3 < NN) { rowptr[base + 3] = excl; cursor[base + 3] = excl; }
}

// ---- edge pass 2: bucket (row, norm) by col ----
__global__ void k_edge2(const int* __restrict__ ei, const float* __restrict__ ew,
                        const float* __restrict__ dinv, int* __restrict__ cursor,
                        int* __restrict__ srow, float* __restrict__ snorm) {
  int e = blockIdx.x * 256 + threadIdx.x;
  if (e < EE) {
    int r = ei[e], c = ei[EE + e];
    float nrm = dinv[r] * ew[e] * dinv[c];
    int pos = atomicAdd(cursor + c, 1);
    srow[pos] = r;
    snorm[pos] = nrm;
  }
}

// ---- dual GEMM (swapped operands): tmp = H@Wl^T (f32), hg = H@Wg^T (bf16)
// mfma(first=W, second=H): D row-formula -> W-row (channel), D col (lane&15) -> H-row (node)
// => lane (m=lane&15, g=lane>>4) holds 4 consecutive channels for node row0+m -> f32x4 store.
__global__ __launch_bounds__(256) void k_dualgemm(const float* __restrict__ H,
    const short* __restrict__ Wl, const short* __restrict__ Wg,
    float* __restrict__ tmp, unsigned short* __restrict__ hg) {
  int wid = (blockIdx.x * 256 + (int)threadIdx.x) >> 6;
  int lane = threadIdx.x & 63;
  if (wid >= NN / 16) return;
  int row0 = wid << 4;
  int m = lane & 15, g = lane >> 4;

  // H fragments (second operand): H[row0+m][s*32 + g*8 + j]
  const float* hrow = H + (size_t)(row0 + m) * DD + g * 8;
  bf16x8 b[4];
#pragma unroll
  for (int s = 0; s < 4; ++s) {
    f32x4 v0 = *(const f32x4*)(hrow + s * 32);
    f32x4 v1 = *(const f32x4*)(hrow + s * 32 + 4);
    bf16x8 t;
    t[0] = f2bf(v0[0]); t[1] = f2bf(v0[1]); t[2] = f2bf(v0[2]); t[3] = f2bf(v0[3]);
    t[4] = f2bf(v1[0]); t[5] = f2bf(v1[1]); t[6] = f2bf(v1[2]); t[7] = f2bf(v1[3]);
    b[s] = t;
  }

  float* tp = tmp + (size_t)(row0 + m) * DD + g * 4;
  unsigned short* hp = hg + (size_t)(row0 + m) * DD + g * 4;

#pragma unroll
  for (int t = 0; t < 8; ++t) {
    f32x4 al; al[0] = 0.f; al[1] = 0.f; al[2] = 0.f; al[3] = 0.f;
    f32x4 ag = al;
#pragma unroll
    for (int s = 0; s < 4; ++s) {
      int off = (t * 16 + m) * DD + s * 32 + g * 8;  // W[channel][k]
      bf16x8 wl = *(const bf16x8*)(Wl + off);
      bf16x8 wg = *(const bf16x8*)(Wg + off);
      al = __builtin_amdgcn_mfma_f32_16x16x32_bf16(wl, b[s], al, 0, 0, 0);
      ag = __builtin_amdgcn_mfma_f32_16x16x32_bf16(wg, b[s], ag, 0, 0, 0);
    }
    *(f32x4*)(tp + t * 16) = al;                     // lin branch, f32
    bf16x4 h4;
    h4[0] = f2bf(ag[0]); h4[1] = f2bf(ag[1]); h4[2] = f2bf(ag[2]); h4[3] = f2bf(ag[3]);
    *(bf16x4*)(hp + t * 16) = h4;                    // gcn branch, bf16
  }
}

// ---- aggregation: one wave per node, tmp[node] += sum norm * hg[srcrow] (bf16 gather)
__global__ __launch_bounds__(256) void k_agg(const int* __restrict__ rowptr,
    const int* __restrict__ srow, const float* __restrict__ snorm,
    const unsigned int* __restrict__ hgu, float* __restrict__ tmp) {
  int node = (blockIdx.x * 256 + (int)threadIdx.x) >> 6;
  int lane = threadIdx.x & 63;
  if (node >= NN) return;
  node = __builtin_amdgcn_readfirstlane(node);
  int beg = rowptr[node], end = rowptr[node + 1];
  float ax = 0.f, ay = 0.f;
  for (int j = beg; j < end; ++j) {
    int r = srow[j];
    float w = snorm[j];
    unsigned u = hgu[r * 64 + lane];      // 2 bf16: cols 2*lane, 2*lane+1
    ax += w * bfbits2f(u << 16);
    ay += w * bfbits2f(u & 0xffff0000u);
  }
  float* t = tmp + (size_t)node * DD + lane * 2;
  t[0] += ax;
  t[1] += ay;
}

// ---- BN stats: 2000 blocks x 50 rows, coalesced f32x4, LDS reduce -> partials (no atomics)
__global__ __launch_bounds__(256) void k_bnstats(const float* __restrict__ h,
    float* __restrict__ psum, float* __restrict__ pss) {
  int b = blockIdx.x, t = threadIdx.x;
  int cg = t & 31, rs = t >> 5;          // column group (4 cols), row slice (0..7)
  f32x4 s; s[0] = 0.f; s[1] = 0.f; s[2] = 0.f; s[3] = 0.f;
  f32x4 q = s;
  int r0 = b * RPB;
  for (int r = r0 + rs; r < r0 + RPB; r += 8) {
    f32x4 v = *(const f32x4*)(h + (size_t)r * DD + cg * 4);
    s += v; q += v * v;
  }
  __shared__ f32x4 ls[8][32], lq[8][32];
  ls[rs][cg] = s; lq[rs][cg] = q;
  __syncthreads();
  if (t < 32) {
    f32x4 a = ls[0][t], qq = lq[0][t];
#pragma unroll
    for (int k = 1; k < 8; ++k) { a += ls[k][t]; qq += lq[k][t]; }
#pragma unroll
    for (int c = 0; c < 4; ++c) {
      psum[(t * 4 + c) * NPB + b] = a[c];
      pss [(t * 4 + c) * NPB + b] = qq[c];
    }
  }
}

// ---- reduce partials -> per-column scale/bias (folds gamma/beta/rsqrt) ----
__global__ __launch_bounds__(256) void k_bnreduce(const float* __restrict__ psum,
    const float* __restrict__ pss, const float* __restrict__ gamma,
    const float* __restrict__ beta, float* __restrict__ sb) {
  int col = blockIdx.x, t = threadIdx.x;
  float s = 0.f, q = 0.f;
  for (int i = t; i < NPB; i += 256) { s += psum[col * NPB + i]; q += pss[col * NPB + i]; }
  for (int d = 32; d > 0; d >>= 1) { s += __shfl_down(s, d); q += __shfl_down(q, d); }
  __shared__ float lws[4], lwq[4];
  int wid = t >> 6, lane = t & 63;
  if (lane == 0) { lws[wid] = s; lwq[wid] = q; }
  __syncthreads();
  if (t == 0) {
    float S = lws[0] + lws[1] + lws[2] + lws[3];
    float Q = lwq[0] + lwq[1] + lwq[2] + lwq[3];
    float mean = S * (1.f / NN);
    float var = Q * (1.f / NN) - mean * mean;
    float sc = rsqrtf(var + EPSV) * gamma[col];
    sb[col] = sc;
    sb[DD + col] = beta[col] - mean * sc;
  }
}

// ---- BN apply (+ optional ReLU): x*scale + bias ----
__global__ void k_bnapply(const float* __restrict__ h, const float* __restrict__ sb,
                          float* __restrict__ out, int relu) {
  int i = blockIdx.x * 256 + threadIdx.x;
  if (i >= NN * DD / 4) return;
  int d0 = (i * 4) & (DD - 1);
  f32x4 v = ((const f32x4*)h)[i];
  f32x4 o;
#pragma unroll
  for (int c = 0; c < 4; ++c) {
    float x = v[c] * sb[d0 + c] + sb[DD + d0 + c];
    o[c] = relu ? fmaxf(x, 0.f) : x;
  }
  ((f32x4*)out)[i] = o;
}

extern "C" void kernel_launch(void* const* d_in, const int* in_sizes, int n_in,
                              void* d_out, int out_size, void* d_ws, size_t ws_size,
                              hipStream_t stream) {
  const float* x     = (const float*)d_in[0];
  const int*   ei    = (const int*)d_in[1];
  const float* ew    = (const float*)d_in[2];
  const float* lin_w = (const float*)d_in[3];
  const float* gcn_w = (const float*)d_in[4];
  const float* gamma = (const float*)d_in[5];
  const float* beta  = (const float*)d_in[6];
  float* out = (float*)d_out;

  char* ws = (char*)d_ws;
  size_t off = 0;
  auto alloc = [&](size_t bytes) -> void* {
    void* p = ws + off;
    off += (bytes + 255) & ~(size_t)255;
    return p;
  };
  unsigned short* hg = (unsigned short*)alloc((size_t)NN * DD * 2);  // bf16
  float* tmp    = (float*)alloc((size_t)NN * DD * 4);
  float* snorm  = (float*)alloc((size_t)EE * 4);
  int*   srow   = (int*)alloc((size_t)EE * 4);
  float* deg    = (float*)alloc((size_t)NN * 4);
  float* dinv   = (float*)alloc((size_t)NN * 4);
  int*   rowptr = (int*)alloc((size_t)(NN + 1) * 4);
  int*   cursor = (int*)alloc((size_t)NN * 4);
  int*   cnt    = (int*)alloc((size_t)NN * 4);
  int*   part   = (int*)alloc((size_t)NBLK * 4);
  short* wbf    = (short*)alloc((size_t)2 * NDEPTH * DD * DD * 2);
  float* psum   = (float*)alloc((size_t)DD * NPB * 4);
  float* pss    = (float*)alloc((size_t)DD * NPB * 4);
  float* sb     = (float*)alloc((size_t)2 * DD * 4);

  hipMemsetAsync(deg, 0, (size_t)NN * 4, stream);
  hipMemsetAsync(cnt, 0, (size_t)NN * 4, stream);

  k_convert_w<<<(NDEPTH * DD * DD + 255) / 256, 256, 0, stream>>>(lin_w, gcn_w, wbf);
  k_edge1<<<(EE + 255) / 256, 256, 0, stream>>>(ei, ew, deg, cnt);
  k_dinv<<<(NN + 255) / 256, 256, 0, stream>>>(deg, dinv);
  k_scan_part<<<NBLK, 256, 0, stream>>>(cnt, part);
  k_scan_mid<<<1, 128, 0, stream>>>(part, rowptr);
  k_scan_final<<<NBLK, 256, 0, stream>>>(cnt, part, rowptr, cursor);
  k_edge2<<<(EE + 255) / 256, 256, 0, stream>>>(ei, ew, dinv, cursor, srow, snorm);

  const float* hin = x;
  for (int L = 0; L < NDEPTH; ++L) {
    const short* Wl = wbf + (size_t)L * DD * DD;
    const short* Wg = wbf + (size_t)NDEPTH * DD * DD + (size_t)L * DD * DD;
    k_dualgemm<<<(NN / 16 + 3) / 4, 256, 0, stream>>>(hin, Wl, Wg, tmp, hg);
    k_agg<<<(NN + 3) / 4, 256, 0, stream>>>(rowptr, srow, snorm, (const unsigned int*)hg, tmp);
    k_bnstats<<<NPB, 256, 0, stream>>>(tmp, psum, pss);
    k_bnreduce<<<DD, 256, 0, stream>>>(psum, pss, gamma + (size_t)L * DD,
                                       beta + (size_t)L * DD, sb);
    k_bnapply<<<(NN * DD / 4 + 255) / 256, 256, 0, stream>>>(
        tmp, sb, out, (L < NDEPTH - 1) ? 1 : 0);
    hin = out;
  }
}

// Round 7
// 332.130 us; speedup vs baseline: 2.1393x; 1.1794x over previous
//
#include <hip/hip_runtime.h>
#include <hip/hip_bf16.h>

#define NN 100000
#define EE 500000
#define DD 128
#define NDEPTH 2
#define EPSV 1e-5f
#define NCHUNK 1024
#define NBLK ((NN + NCHUNK - 1) / NCHUNK)   // 98
#define NPB 2000     // bnstats blocks
#define RPB 50       // rows per bnstats block (2000*50 = 100000)

typedef __attribute__((ext_vector_type(4))) float f32x4;
typedef __attribute__((ext_vector_type(4))) int i32x4;
typedef __attribute__((ext_vector_type(8))) short bf16x8;
typedef __attribute__((ext_vector_type(4))) short bf16x4;

static __device__ __forceinline__ short f2bf(float x) {
  union { float f; unsigned u; } v; v.f = x;
  unsigned r = v.u + 0x7fffu + ((v.u >> 16) & 1u);  // round-to-nearest-even
  return (short)(r >> 16);
}
static __device__ __forceinline__ float bfbits2f(unsigned hi16) {
  union { unsigned u; float f; } v; v.u = hi16;
  return v.f;
}

// ---- convert both weight tensors to bf16 once ----
__global__ void k_convert_w(const float* __restrict__ lw, const float* __restrict__ gw,
                            short* __restrict__ wbf) {
  int i = blockIdx.x * 256 + threadIdx.x;
  if (i < NDEPTH * DD * DD) {
    wbf[i] = f2bf(lw[i]);
    wbf[NDEPTH * DD * DD + i] = f2bf(gw[i]);
  }
}

// ---- edge pass 1: degree (weighted) + count histogram by col ----
__global__ void k_edge1(const int* __restrict__ ei, const float* __restrict__ ew,
                        float* __restrict__ deg, int* __restrict__ cnt) {
  int e = blockIdx.x * 256 + threadIdx.x;
  if (e < EE) {
    int c = ei[EE + e];
    atomicAdd(deg + c, ew[e]);
    atomicAdd(cnt + c, 1);
  }
}

__global__ void k_dinv(const float* __restrict__ deg, float* __restrict__ dinv) {
  int i = blockIdx.x * 256 + threadIdx.x;
  if (i < NN) {
    float d = deg[i];
    dinv[i] = d > 0.f ? rsqrtf(d) : 0.f;
  }
}

// ---- scan stage 1: per-chunk (1024 elems) sums ----
__global__ __launch_bounds__(256) void k_scan_part(const int* __restrict__ cnt,
                                                   int* __restrict__ part) {
  int b = blockIdx.x, t = threadIdx.x, lane = t & 63, wid = t >> 6;
  int base = b * NCHUNK + t * 4;
  int s = 0;
  if (base + 3 < NN) {
    i32x4 v = *(const i32x4*)(cnt + base);
    s = v[0] + v[1] + v[2] + v[3];
  } else {
    for (int j = 0; j < 4; ++j) if (base + j < NN) s += cnt[base + j];
  }
  for (int d = 32; d > 0; d >>= 1) s += __shfl_down(s, d);
  __shared__ int wsum[4];
  if (lane == 0) wsum[wid] = s;
  __syncthreads();
  if (t == 0) part[b] = wsum[0] + wsum[1] + wsum[2] + wsum[3];
}

// ---- scan stage 2: exclusive scan of the 98 partials ----
__global__ void k_scan_mid(int* __restrict__ part, int* __restrict__ rowptr) {
  __shared__ int sm[128];
  int t = threadIdx.x;
  int v = (t < NBLK) ? part[t] : 0;
  sm[t] = v;
  __syncthreads();
  for (int off = 1; off < 128; off <<= 1) {
    int a = sm[t];
    int b = (t >= off) ? sm[t - off] : 0;
    __syncthreads();
    sm[t] = a + b;
    __syncthreads();
  }
  if (t < NBLK) part[t] = (t == 0) ? 0 : sm[t - 1];
  if (t == 127) rowptr[NN] = sm[127];
}

// ---- scan stage 3: per-chunk exclusive scan -> rowptr, cursor ----
__global__ __launch_bounds__(256) void k_scan_final(const int* __restrict__ cnt,
    const int* __restrict__ part, int* __restrict__ rowptr, int* __restrict__ cursor) {
  int b = blockIdx.x, t = threadIdx.x, lane = t & 63, wid = t >> 6;
  int base = b * NCHUNK + t * 4;
  int c0 = 0, c1 = 0, c2 = 0, c3 = 0;
  if (base + 3 < NN) {
    i32x4 v = *(const i32x4*)(cnt + base);
    c0 = v[0]; c1 = v[1]; c2 = v[2]; c3 = v[3];
  } else {
    if (base < NN) c0 = cnt[base];
    if (base + 1 < NN) c1 = cnt[base + 1];
    if (base + 2 < NN) c2 = cnt[base + 2];
    if (base + 3 < NN) c3 = cnt[base + 3];
  }
  int s = c0 + c1 + c2 + c3;
  int v = s;
  for (int d = 1; d < 64; d <<= 1) {
    int u = __shfl_up(v, d);
    if (lane >= d) v += u;
  }
  __shared__ int wsum[4];
  if (lane == 63) wsum[wid] = v;
  __syncthreads();
  int woff = 0;
  for (int w = 0; w < wid; ++w) woff += wsum[w];
  int excl = part[b] + woff + (v - s);
  if (base < NN)     { rowptr[base]     = excl; cursor[base]     = excl; excl += c0; }
  if (base + 1 < NN) { rowptr[base + 1] = excl; cursor[base + 1] = excl; excl += c1; }
  if (base + 2 < NN) { rowptr[base + 2] = excl; cursor[base + 2] = excl; excl += c2; }
  if (base + 3 < NN) { rowptr[base + 3] = excl; cursor[base + 3] = excl; }
}

// ---- edge pass 2: bucket (row, norm) by col ----
__global__ void k_edge2(const int* __restrict__ ei, const float* __restrict__ ew,
                        const float* __restrict__ dinv, int* __restrict__ cursor,
                        int* __restrict__ srow, float* __restrict__ snorm) {
  int e = blockIdx.x * 256 + threadIdx.x;
  if (e < EE) {
    int r = ei[e], c = ei[EE + e];
    float nrm = dinv[r] * ew[e] * dinv[c];
    int pos = atomicAdd(cursor + c, 1);
    srow[pos] = r;
    snorm[pos] = nrm;
  }
}

// ---- dual GEMM, J=4 row-groups per wave (64 rows): tmp = H@Wl^T (f32), hg = H@Wg^T (bf16)
// Swapped operands: mfma(first=W, second=H) => lane m=lane&15 -> node row, g=lane>>4
// with acc idx i -> channel t*16 + g*4 + i (4 consecutive channels -> f32x4 store).
// W fragments loaded once per (t,s) and reused across 4 row-groups (8 indep acc chains).
__global__ __launch_bounds__(256) void k_dualgemm(const float* __restrict__ H,
    const short* __restrict__ Wl, const short* __restrict__ Wg,
    float* __restrict__ tmp, unsigned short* __restrict__ hg) {
  int wid = (blockIdx.x * 256 + (int)threadIdx.x) >> 6;
  int lane = threadIdx.x & 63;
  int row0 = wid * 64;
  if (row0 >= NN) return;
  int m = lane & 15, g = lane >> 4;

  // H fragments for 4 row-groups: H[row0+jj*16+m][s*32 + g*8 + j]
  bf16x8 b[4][4];
  bool act[4];
#pragma unroll
  for (int jj = 0; jj < 4; ++jj) {
    act[jj] = (row0 + jj * 16) < NN;   // NN % 16 == 0, so whole groups drop out
    int r = act[jj] ? (row0 + jj * 16 + m) : m;
    const float* hrow = H + (size_t)r * DD + g * 8;
#pragma unroll
    for (int s = 0; s < 4; ++s) {
      f32x4 v0 = *(const f32x4*)(hrow + s * 32);
      f32x4 v1 = *(const f32x4*)(hrow + s * 32 + 4);
      bf16x8 t;
      t[0] = f2bf(v0[0]); t[1] = f2bf(v0[1]); t[2] = f2bf(v0[2]); t[3] = f2bf(v0[3]);
      t[4] = f2bf(v1[0]); t[5] = f2bf(v1[1]); t[6] = f2bf(v1[2]); t[7] = f2bf(v1[3]);
      b[jj][s] = t;
    }
  }

#pragma unroll
  for (int t = 0; t < 8; ++t) {
    f32x4 accl[4], accg[4];
#pragma unroll
    for (int jj = 0; jj < 4; ++jj) {
      f32x4 z; z[0] = 0.f; z[1] = 0.f; z[2] = 0.f; z[3] = 0.f;
      accl[jj] = z; accg[jj] = z;
    }
#pragma unroll
    for (int s = 0; s < 4; ++s) {
      int off = (t * 16 + m) * DD + s * 32 + g * 8;  // W[channel][k]
      bf16x8 wl = *(const bf16x8*)(Wl + off);
      bf16x8 wg = *(const bf16x8*)(Wg + off);
#pragma unroll
      for (int jj = 0; jj < 4; ++jj) {
        accl[jj] = __builtin_amdgcn_mfma_f32_16x16x32_bf16(wl, b[jj][s], accl[jj], 0, 0, 0);
        accg[jj] = __builtin_amdgcn_mfma_f32_16x16x32_bf16(wg, b[jj][s], accg[jj], 0, 0, 0);
      }
    }
#pragma unroll
    for (int jj = 0; jj < 4; ++jj) {
      if (!act[jj]) continue;
      size_t r = (size_t)(row0 + jj * 16 + m);
      *(f32x4*)(tmp + r * DD + t * 16 + g * 4) = accl[jj];
      bf16x4 h4;
      h4[0] = f2bf(accg[jj][0]); h4[1] = f2bf(accg[jj][1]);
      h4[2] = f2bf(accg[jj][2]); h4[3] = f2bf(accg[jj][3]);
      *(bf16x4*)(hg + r * DD + t * 16 + g * 4) = h4;
    }
  }
}

// ---- aggregation: one wave per node, tmp[node] += sum norm * hg[srcrow] (bf16 gather)
__global__ __launch_bounds__(256) void k_agg(const int* __restrict__ rowptr,
    const int* __restrict__ srow, const float* __restrict__ snorm,
    const unsigned int* __restrict__ hgu, float* __restrict__ tmp) {
  int node = (blockIdx.x * 256 + (int)threadIdx.x) >> 6;
  int lane = threadIdx.x & 63;
  if (node >= NN) return;
  node = __builtin_amdgcn_readfirstlane(node);
  int beg = rowptr[node], end = rowptr[node + 1];
  float ax = 0.f, ay = 0.f;
  for (int j = beg; j < end; ++j) {
    int r = srow[j];
    float w = snorm[j];
    unsigned u = hgu[r * 64 + lane];      // 2 bf16: cols 2*lane, 2*lane+1
    ax += w * bfbits2f(u << 16);
    ay += w * bfbits2f(u & 0xffff0000u);
  }
  float* t = tmp + (size_t)node * DD + lane * 2;
  t[0] += ax;
  t[1] += ay;
}

// ---- BN stats: 2000 blocks x 50 rows, coalesced f32x4, LDS reduce -> partials (no atomics)
__global__ __launch_bounds__(256) void k_bnstats(const float* __restrict__ h,
    float* __restrict__ psum, float* __restrict__ pss) {
  int b = blockIdx.x, t = threadIdx.x;
  int cg = t & 31, rs = t >> 5;          // column group (4 cols), row slice (0..7)
  f32x4 s; s[0] = 0.f; s[1] = 0.f; s[2] = 0.f; s[3] = 0.f;
  f32x4 q = s;
  int r0 = b * RPB;
  for (int r = r0 + rs; r < r0 + RPB; r += 8) {
    f32x4 v = *(const f32x4*)(h + (size_t)r * DD + cg * 4);
    s += v; q += v * v;
  }
  __shared__ f32x4 ls[8][32], lq[8][32];
  ls[rs][cg] = s; lq[rs][cg] = q;
  __syncthreads();
  if (t < 32) {
    f32x4 a = ls[0][t], qq = lq[0][t];
#pragma unroll
    for (int k = 1; k < 8; ++k) { a += ls[k][t]; qq += lq[k][t]; }
#pragma unroll
    for (int c = 0; c < 4; ++c) {
      psum[(t * 4 + c) * NPB + b] = a[c];
      pss [(t * 4 + c) * NPB + b] = qq[c];
    }
  }
}

// ---- reduce partials -> per-column scale/bias (folds gamma/beta/rsqrt) ----
__global__ __launch_bounds__(256) void k_bnreduce(const float* __restrict__ psum,
    const float* __restrict__ pss, const float* __restrict__ gamma,
    const float* __restrict__ beta, float* __restrict__ sb) {
  int col = blockIdx.x, t = threadIdx.x;
  float s = 0.f, q = 0.f;
  for (int i = t; i < NPB; i += 256) { s += psum[col * NPB + i]; q += pss[col * NPB + i]; }
  for (int d = 32; d > 0; d >>= 1) { s += __shfl_down(s, d); q += __shfl_down(q, d); }
  __shared__ float lws[4], lwq[4];
  int wid = t >> 6, lane = t & 63;
  if (lane == 0) { lws[wid] = s; lwq[wid] = q; }
  __syncthreads();
  if (t == 0) {
    float S = lws[0] + lws[1] + lws[2] + lws[3];
    float Q = lwq[0] + lwq[1] + lwq[2] + lwq[3];
    float mean = S * (1.f / NN);
    float var = Q * (1.f / NN) - mean * mean;
    float sc = rsqrtf(var + EPSV) * gamma[col];
    sb[col] = sc;
    sb[DD + col] = beta[col] - mean * sc;
  }
}

// ---- BN apply (+ optional ReLU): x*scale + bias ----
__global__ void k_bnapply(const float* __restrict__ h, const float* __restrict__ sb,
                          float* __restrict__ out, int relu) {
  int i = blockIdx.x * 256 + threadIdx.x;
  if (i >= NN * DD / 4) return;
  int d0 = (i * 4) & (DD - 1);
  f32x4 v = ((const f32x4*)h)[i];
  f32x4 o;
#pragma unroll
  for (int c = 0; c < 4; ++c) {
    float x = v[c] * sb[d0 + c] + sb[DD + d0 + c];
    o[c] = relu ? fmaxf(x, 0.f) : x;
  }
  ((f32x4*)out)[i] = o;
}

extern "C" void kernel_launch(void* const* d_in, const int* in_sizes, int n_in,
                              void* d_out, int out_size, void* d_ws, size_t ws_size,
                              hipStream_t stream) {
  const float* x     = (const float*)d_in[0];
  const int*   ei    = (const int*)d_in[1];
  const float* ew    = (const float*)d_in[2];
  const float* lin_w = (const float*)d_in[3];
  const float* gcn_w = (const float*)d_in[4];
  const float* gamma = (const float*)d_in[5];
  const float* beta  = (const float*)d_in[6];
  float* out = (float*)d_out;

  char* ws = (char*)d_ws;
  size_t off = 0;
  auto alloc = [&](size_t bytes) -> void* {
    void* p = ws + off;
    off += (bytes + 255) & ~(size_t)255;
    return p;
  };
  unsigned short* hg = (unsigned short*)alloc((size_t)NN * DD * 2);  // bf16
  float* tmp    = (float*)alloc((size_t)NN * DD * 4);
  float* snorm  = (float*)alloc((size_t)EE * 4);
  int*   srow   = (int*)alloc((size_t)EE * 4);
  float* deg    = (float*)alloc((size_t)NN * 4);
  float* dinv   = (float*)alloc((size_t)NN * 4);
  int*   rowptr = (int*)alloc((size_t)(NN + 1) * 4);
  int*   cursor = (int*)alloc((size_t)NN * 4);
  int*   cnt    = (int*)alloc((size_t)NN * 4);
  int*   part   = (int*)alloc((size_t)NBLK * 4);
  short* wbf    = (short*)alloc((size_t)2 * NDEPTH * DD * DD * 2);
  float* psum   = (float*)alloc((size_t)DD * NPB * 4);
  float* pss    = (float*)alloc((size_t)DD * NPB * 4);
  float* sb     = (float*)alloc((size_t)2 * DD * 4);

  hipMemsetAsync(deg, 0, (size_t)NN * 4, stream);
  hipMemsetAsync(cnt, 0, (size_t)NN * 4, stream);

  k_convert_w<<<(NDEPTH * DD * DD + 255) / 256, 256, 0, stream>>>(lin_w, gcn_w, wbf);
  k_edge1<<<(EE + 255) / 256, 256, 0, stream>>>(ei, ew, deg, cnt);
  k_dinv<<<(NN + 255) / 256, 256, 0, stream>>>(deg, dinv);
  k_scan_part<<<NBLK, 256, 0, stream>>>(cnt, part);
  k_scan_mid<<<1, 128, 0, stream>>>(part, rowptr);
  k_scan_final<<<NBLK, 256, 0, stream>>>(cnt, part, rowptr, cursor);
  k_edge2<<<(EE + 255) / 256, 256, 0, stream>>>(ei, ew, dinv, cursor, srow, snorm);

  const float* hin = x;
  for (int L = 0; L < NDEPTH; ++L) {
    const short* Wl = wbf + (size_t)L * DD * DD;
    const short* Wg = wbf + (size_t)NDEPTH * DD * DD + (size_t)L * DD * DD;
    // 64 rows per wave, 4 waves per block -> 256 rows per block
    k_dualgemm<<<(NN + 255) / 256, 256, 0, stream>>>(hin, Wl, Wg, tmp, hg);
    k_agg<<<(NN + 3) / 4, 256, 0, stream>>>(rowptr, srow, snorm, (const unsigned int*)hg, tmp);
    k_bnstats<<<NPB, 256, 0, stream>>>(tmp, psum, pss);
    k_bnreduce<<<DD, 256, 0, stream>>>(psum, pss, gamma + (size_t)L * DD,
                                       beta + (size_t)L * DD, sb);
    k_bnapply<<<(NN * DD / 4 + 255) / 256, 256, 0, stream>>>(
        tmp, sb, out, (L < NDEPTH - 1) ? 1 : 0);
    hin = out;
  }
}